// Round 11
// baseline (131.462 us; speedup 1.0000x reference)
//
#include <hip/hip_runtime.h>

// Bahdanau additive attention: B=8, TE=512, TD=256, H=256, fp32.
//   We = enc @ W_a; Uh = dec @ U_a
//   e[b,j,i] = softmax_i( sum_h V[h]*tanh(We[b,i,h]+Uh[b,j,h]) )
//   c[b,j,h] = sum_i e[b,j,i]*enc[b,i,h]
// d_out = [c (B*TD*H)] ++ [e (B*TD*TE)]
//
// R19 (this round): CONVOY-BREAKING. Ledger: phase A idles 50% of VALU
// cycles and is immune to barriers(R10), vector prefetch(R11), SMEM->LDS
// (R12), occupancy(R13/14), VALU count(R16), traffic(R17), SMEM width(R18).
// Remaining consistent mechanism: wave CONVOY -- all 8 waves run identical
// code from a common start, issue their u/v loads in the same window, and
// all stall together (util ~ compute/(compute+latency) ~ 50%, stable under
// jitter, occupancy-proof). Fix: per-wave rotation of the q-loop (phase A,
// qoff = wv*8, mod-64) and the k-loop (phase B) so load windows of one
// wave overlap compute windows of the others. Zero extra instructions;
// only per-accumulator summation ORDER changes (absmax ~1e-6 shift).
// R15 keeps: 2-kernel config, fused weight-transpose k_pre (verbatim).
// R11 keeps: 2-deep named-reg prefetch (w4, enc). R9: split-bf16 MFMA.
// R8: 4-way rcp batching. R7: XCD swizzle (b = blockIdx&7), W4 layout.

#define BB 8
#define TE 512
#define TD 256
#define HH 256

#define EXP2F(x) __builtin_amdgcn_exp2f(x)
#define RCPF(x)  __builtin_amdgcn_rcpf(x)
#define KSCALE   2.8853900817779268f    // 2*log2(e)
#define NSC      (-2.8853900817779268f) // -2*log2(e)

typedef __attribute__((ext_vector_type(8))) short short8_t;  // 8 bf16 = 4 VGPR
typedef __attribute__((ext_vector_type(4))) float f32x4;     // MFMA acc

__device__ __forceinline__ unsigned short f2bf(float x) {
    unsigned int u = __float_as_uint(x);
    return (unsigned short)((u + 0x7FFFu + ((u >> 16) & 1u)) >> 16);  // RNE
}
__device__ __forceinline__ float bf2f(unsigned short h) {
    return __uint_as_float(((unsigned int)h) << 16);
}

// ---------------------------------------------------------------------------
// k_pre (R15, verbatim): split-bf16 MFMA GEMM over X = [enc; dec], D[h][i],
// fused weight transpose. Tile 64h x 64i, 384 blocks, K-chunks of 32.
// Fragment layouts (m89-verified):
//   A/B frags: row/col = l&15, k-octet = (l>>4)*8; D: col=l&15, row=(l>>4)*4+reg.
// ---------------------------------------------------------------------------
__global__ __launch_bounds__(256) void k_pre(
    const float* __restrict__ enc, const float* __restrict__ dec,
    const float* __restrict__ Wa,  const float* __restrict__ Ua,
    float* __restrict__ W4, float* __restrict__ Uhe)
{
    const int t  = threadIdx.x;
    const int it = blockIdx.x >> 2;       // 0..95  (i-tile)
    const int ht = blockIdx.x & 3;        // 0..3   (h-tile)
    const int i0 = it * 64;
    const int h0 = ht * 64;
    const bool is_enc = (i0 < BB * TE);   // < 4096
    const float* X  = is_enc ? (enc + (size_t)i0 * HH)
                             : (dec + (size_t)(i0 - BB * TE) * HH);
    const float* Wg = is_enc ? Wa : Ua;

    __shared__ unsigned short At_h[64][40], At_l[64][40];
    __shared__ unsigned short Xs_h[64][40], Xs_l[64][40];
    __shared__ float T[32][66];           // fp32 W chunk, padded

    const int sr = t >> 2;                // X staging row / At pass-2 h (0..63)
    const int sq = (t & 3) * 8;           // k-octet (0,8,16,24)
    const int kr = t >> 3;                // W load k-row (0..31)
    const int hc = (t & 7) * 8;           // W load h-base (0..56)

    const int wv = t >> 6, l = t & 63;
    const int wh = (wv & 1) * 32;
    const int wi = (wv >> 1) * 32;
    const int fr = l & 15;
    const int fk = (l >> 4) * 8;
    const int rq = l >> 4;                // D row-quad

    f32x4 acc[2][2];
    #pragma unroll
    for (int a0 = 0; a0 < 2; a0++)
        #pragma unroll
        for (int a1 = 0; a1 < 2; a1++)
            acc[a0][a1] = (f32x4){0.f, 0.f, 0.f, 0.f};

    float4 x0  = *(const float4*)(X + (size_t)sr * HH + sq);
    float4 x1  = *(const float4*)(X + (size_t)sr * HH + sq + 4);
    float4 wf0 = *(const float4*)(Wg + (size_t)kr * HH + h0 + hc);
    float4 wf1 = *(const float4*)(Wg + (size_t)kr * HH + h0 + hc + 4);

    #pragma unroll
    for (int c = 0; c < 8; c++) {
        short8_t xh, xl;
        {
            unsigned short h;
            h = f2bf(x0.x); xh[0] = (short)h; xl[0] = (short)f2bf(x0.x - bf2f(h));
            h = f2bf(x0.y); xh[1] = (short)h; xl[1] = (short)f2bf(x0.y - bf2f(h));
            h = f2bf(x0.z); xh[2] = (short)h; xl[2] = (short)f2bf(x0.z - bf2f(h));
            h = f2bf(x0.w); xh[3] = (short)h; xl[3] = (short)f2bf(x0.w - bf2f(h));
            h = f2bf(x1.x); xh[4] = (short)h; xl[4] = (short)f2bf(x1.x - bf2f(h));
            h = f2bf(x1.y); xh[5] = (short)h; xl[5] = (short)f2bf(x1.y - bf2f(h));
            h = f2bf(x1.z); xh[6] = (short)h; xl[6] = (short)f2bf(x1.z - bf2f(h));
            h = f2bf(x1.w); xh[7] = (short)h; xl[7] = (short)f2bf(x1.w - bf2f(h));
        }
        __syncthreads();   // B1: prior chunk's MFMA readers done
        *(short8_t*)&Xs_h[sr][sq] = xh;
        *(short8_t*)&Xs_l[sr][sq] = xl;
        {
            float2 a, b;
            a.x = wf0.x; a.y = wf0.y; b.x = wf0.z; b.y = wf0.w;
            *(float2*)&T[kr][hc]     = a;
            *(float2*)&T[kr][hc + 2] = b;
            a.x = wf1.x; a.y = wf1.y; b.x = wf1.z; b.y = wf1.w;
            *(float2*)&T[kr][hc + 4] = a;
            *(float2*)&T[kr][hc + 6] = b;
        }
        __syncthreads();   // B2: T + Xs ready
        {
            short8_t ah_, al_;
            #pragma unroll
            for (int e = 0; e < 8; e++) {
                float f = T[sq + e][sr];
                unsigned short h = f2bf(f);
                ah_[e] = (short)h;
                al_[e] = (short)f2bf(f - bf2f(h));
            }
            *(short8_t*)&At_h[sr][sq] = ah_;
            *(short8_t*)&At_l[sr][sq] = al_;
        }
        if (c < 7) {
            const int kc = (c + 1) * 32;
            x0  = *(const float4*)(X + (size_t)sr * HH + kc + sq);
            x1  = *(const float4*)(X + (size_t)sr * HH + kc + sq + 4);
            wf0 = *(const float4*)(Wg + (size_t)(kc + kr) * HH + h0 + hc);
            wf1 = *(const float4*)(Wg + (size_t)(kc + kr) * HH + h0 + hc + 4);
        }
        __syncthreads();   // B3: At ready
        #pragma unroll
        for (int fm = 0; fm < 2; fm++) {
            short8_t a_h = *(const short8_t*)&At_h[wh + 16 * fm + fr][fk];
            short8_t a_l = *(const short8_t*)&At_l[wh + 16 * fm + fr][fk];
            #pragma unroll
            for (int fn = 0; fn < 2; fn++) {
                short8_t b_h = *(const short8_t*)&Xs_h[wi + 16 * fn + fr][fk];
                short8_t b_l = *(const short8_t*)&Xs_l[wi + 16 * fn + fr][fk];
                acc[fm][fn] = __builtin_amdgcn_mfma_f32_16x16x32_bf16(a_h, b_h, acc[fm][fn], 0, 0, 0);
                acc[fm][fn] = __builtin_amdgcn_mfma_f32_16x16x32_bf16(a_h, b_l, acc[fm][fn], 0, 0, 0);
                acc[fm][fn] = __builtin_amdgcn_mfma_f32_16x16x32_bf16(a_l, b_h, acc[fm][fn], 0, 0, 0);
            }
        }
    }

    #pragma unroll
    for (int fm = 0; fm < 2; fm++) {
        #pragma unroll
        for (int fn = 0; fn < 2; fn++) {
            f32x4 v = acc[fm][fn];
            float4 o;
            o.x = EXP2F(v[0] * KSCALE);
            o.y = EXP2F(v[1] * KSCALE);
            o.z = EXP2F(v[2] * KSCALE);
            o.w = EXP2F(v[3] * KSCALE);
            const int ig = i0 + wi + 16 * fn + fr;      // global concat row
            const int hb = h0 + wh + 16 * fm + rq * 4;  // 4 consecutive h
            if (is_enc) {
                const int b  = ig >> 9;                 // 512 enc rows per batch
                const int ib = ig & 511;
                const int hq = hb >> 2;
                *(float4*)(W4 + (((size_t)b * 64 + hq) * TE + ib) * 4) = o;
            } else {
                const int j = ig - BB * TE;             // global dec row
                *(float4*)(Uhe + (size_t)j * HH + hb) = o;
            }
        }
    }
}

// ---------------------------------------------------------------------------
// k_attn (R19): 512 threads = 8 waves; block owns 4 consecutive j's of ONE
// batch, batch = blockIdx&7 (XCD-local).
// Phase A: wave wv starts its q-loop at qoff = wv*8 (mod-64 wrap) so the
// 8 waves' load windows are staggered across the iteration space instead
// of convoying. 2-deep named-reg prefetch of the w4 stream (wrapped).
// Softmax: waves 0-3. Phase B: same stagger on the enc k-loop.
// Accumulation order is a rotation of the same 64 terms per accumulator.
// ---------------------------------------------------------------------------
__global__ __launch_bounds__(512) void k_attn(
    const float* __restrict__ enc, const float* __restrict__ W4,
    const float* __restrict__ Uhe, const float* __restrict__ Va,
    float* __restrict__ out_c, float* __restrict__ out_e)
{
    const int wv = threadIdx.x >> 6, lane = threadIdx.x & 63;
    const int b   = blockIdx.x & 7;           // XCD-local batch
    const int j0  = (blockIdx.x >> 3) * 4;    // 64 j-groups per batch
    const int jj0 = b * TD + j0;              // block-uniform

    __shared__ float sP[4][TE];      // 8 KB: energies -> probabilities
    __shared__ float sR[8][4][HH];   // 32 KB: phase-B partials

    const int i = (wv << 6) + lane;
    const float* wp = W4 + ((size_t)b * 64 * TE + i) * 4;
    const float* ua = Uhe + (size_t)jj0 * HH;   // wave-uniform -> s_load
    const float* va = Va;                        // uniform
    const int qoff = wv << 3;                    // per-wave stagger

    float a0 = 0.f, a1 = 0.f, a2 = 0.f, a3 = 0.f;

    // 4-way batched reciprocal:
    //   sum_k v_k/A_k = (nAB*dCD + nCD*dAB) / (dAB*dCD)
#define QSTEP(ACC, U)                                                     \
    {                                                                     \
        float A_ = fmaf(w4.x, (U).x, 1.f);                                \
        float B_ = fmaf(w4.y, (U).y, 1.f);                                \
        float C_ = fmaf(w4.z, (U).z, 1.f);                                \
        float D_ = fmaf(w4.w, (U).w, 1.f);                                \
        float dAB = A_ * B_, dCD = C_ * D_;                               \
        float nAB = fmaf(v4.x, B_, v4.y * A_);                            \
        float nCD = fmaf(v4.z, D_, v4.w * C_);                            \
        float num = fmaf(nAB, dCD, nCD * dAB);                            \
        ACC = fmaf(num, RCPF(dAB * dCD), ACC);                            \
    }

#define ASTEP(Q, W4V)                                                     \
    {                                                                     \
        float4 w4 = W4V;                                                  \
        float4 v4 = *(const float4*)(va + 4 * (Q));                       \
        float4 u0 = *(const float4*)(ua + 4 * (Q));                       \
        float4 u1 = *(const float4*)(ua + HH + 4 * (Q));                  \
        float4 u2 = *(const float4*)(ua + 2 * HH + 4 * (Q));              \
        float4 u3 = *(const float4*)(ua + 3 * HH + 4 * (Q));              \
        QSTEP(a0, u0)                                                     \
        QSTEP(a1, u1)                                                     \
        QSTEP(a2, u2)                                                     \
        QSTEP(a3, u3)                                                     \
    }

    // 2-deep software pipeline on the per-lane w4 stream, wave-staggered
    float4 wA = *(const float4*)(wp + (size_t)qoff * TE * 4);
    float4 wB = *(const float4*)(wp + (size_t)((qoff + 1) & 63) * TE * 4);
    for (int s = 0; s < 64; s += 2) {
        const int q0 = (s + qoff) & 63;
        const int q1 = (s + 1 + qoff) & 63;
        const int q2 = (s + 2 + qoff) & 63;
        const int q3 = (s + 3 + qoff) & 63;
        float4 wC = *(const float4*)(wp + (size_t)q2 * TE * 4);
        float4 wD = *(const float4*)(wp + (size_t)q3 * TE * 4);
        ASTEP(q0, wA)
        ASTEP(q1, wB)
        wA = wC; wB = wD;
    }
#undef ASTEP
#undef QSTEP

    // conflict-free b32 writes (lane-stride 4B), energies in log2 domain
    sP[0][i] = NSC * a0;
    sP[1][i] = NSC * a1;
    sP[2][i] = NSC * a2;
    sP[3][i] = NSC * a3;
    __syncthreads();

    // ---- softmax: wave w in 0..3 handles j0+w ----------------------------
    if (wv < 4) {
        float ev[8];
        float m = -3.0e38f;
        #pragma unroll
        for (int k = 0; k < 8; k++) {
            ev[k] = sP[wv][lane + 64 * k];
            m = fmaxf(m, ev[k]);
        }
        #pragma unroll
        for (int off = 32; off; off >>= 1) m = fmaxf(m, __shfl_xor(m, off, 64));
        float s = 0.f;
        #pragma unroll
        for (int k = 0; k < 8; k++) { ev[k] = EXP2F(ev[k] - m); s += ev[k]; }
        #pragma unroll
        for (int off = 32; off; off >>= 1) s += __shfl_xor(s, off, 64);
        float rs = RCPF(s);
        float* oe = out_e + (size_t)(jj0 + wv) * TE;
        #pragma unroll
        for (int k = 0; k < 8; k++) {
            float p = ev[k] * rs;
            sP[wv][lane + 64 * k] = p;
            oe[lane + 64 * k] = p;
        }
    }
    __syncthreads();

    // ---- Phase B: wave w -> i in [64w, 64w+64), all 4 j, staggered -------
    const int ib = wv << 6;
    const float* eb = enc + ((size_t)b * TE + ib) * HH + 4 * lane;
    float4 c0 = {0,0,0,0}, c1 = {0,0,0,0}, c2 = {0,0,0,0}, c3 = {0,0,0,0};

#define BSTEP(K, QV)                                                      \
    {                                                                     \
        float p0 = sP[0][ib + (K)];                                       \
        float p1 = sP[1][ib + (K)];                                       \
        float p2 = sP[2][ib + (K)];                                       \
        float p3 = sP[3][ib + (K)];                                       \
        float4 q = QV;                                                    \
        c0.x = fmaf(p0, q.x, c0.x); c0.y = fmaf(p0, q.y, c0.y);           \
        c0.z = fmaf(p0, q.z, c0.z); c0.w = fmaf(p0, q.w, c0.w);           \
        c1.x = fmaf(p1, q.x, c1.x); c1.y = fmaf(p1, q.y, c1.y);           \
        c1.z = fmaf(p1, q.z, c1.z); c1.w = fmaf(p1, q.w, c1.w);           \
        c2.x = fmaf(p2, q.x, c2.x); c2.y = fmaf(p2, q.y, c2.y);           \
        c2.z = fmaf(p2, q.z, c2.z); c2.w = fmaf(p2, q.w, c2.w);           \
        c3.x = fmaf(p3, q.x, c3.x); c3.y = fmaf(p3, q.y, c3.y);           \
        c3.z = fmaf(p3, q.z, c3.z); c3.w = fmaf(p3, q.w, c3.w);           \
    }

    // 2-deep software pipeline on the per-lane enc stream, wave-staggered
    float4 qA = *(const float4*)(eb + (size_t)qoff * HH);
    float4 qB = *(const float4*)(eb + (size_t)((qoff + 1) & 63) * HH);
    for (int s = 0; s < 64; s += 2) {
        const int k0 = (s + qoff) & 63;
        const int k1 = (s + 1 + qoff) & 63;
        const int k2 = (s + 2 + qoff) & 63;
        const int k3 = (s + 3 + qoff) & 63;
        float4 qC = *(const float4*)(eb + (size_t)k2 * HH);
        float4 qD = *(const float4*)(eb + (size_t)k3 * HH);
        BSTEP(k0, qA)
        BSTEP(k1, qB)
        qA = qC; qB = qD;
    }
#undef BSTEP

    *(float4*)&sR[wv][0][4 * lane] = c0;
    *(float4*)&sR[wv][1][4 * lane] = c1;
    *(float4*)&sR[wv][2][4 * lane] = c2;
    *(float4*)&sR[wv][3][4 * lane] = c3;
    __syncthreads();

    // ---- final reduce: wave w -> (j = w&3, h-half = w>>2) ----------------
    {
        const int jr = wv & 3;
        const int h2 = (wv >> 2) * 128 + 2 * lane;
        float sx = 0.f, sy = 0.f;
        #pragma unroll
        for (int ww = 0; ww < 8; ww++) {
            float2 tv = *(const float2*)&sR[ww][jr][h2];
            sx += tv.x; sy += tv.y;
        }
        float2 o; o.x = sx; o.y = sy;
        *(float2*)(out_c + (size_t)(jj0 + jr) * HH + h2) = o;
    }
}

extern "C" void kernel_launch(void* const* d_in, const int* in_sizes, int n_in,
                              void* d_out, int out_size, void* d_ws, size_t ws_size,
                              hipStream_t stream) {
    const float* enc = (const float*)d_in[0];
    const float* dec = (const float*)d_in[1];
    const float* Wa  = (const float*)d_in[2];
    const float* Ua  = (const float*)d_in[3];
    const float* Va  = (const float*)d_in[4];

    float* W4  = (float*)d_ws;                        // exp2-domain, interleaved (4MB)
    float* Uhe = W4 + (size_t)BB * HH * TE;           // exp2-domain, B*TD*H (2MB)

    float* out_c = (float*)d_out;                     // [B,TD,H]
    float* out_e = out_c + (size_t)BB * TD * HH;      // [B,TD,TE]

    k_pre<<<384, 256, 0, stream>>>(enc, dec, Wa, Ua, W4, Uhe);
    k_attn<<<BB * TD / 4, 512, 0, stream>>>(enc, W4, Uhe, Va, out_c, out_e);
}

// Round 12
// 118.023 us; speedup vs baseline: 1.1139x; 1.1139x over previous
//
#include <hip/hip_runtime.h>

// Bahdanau additive attention: B=8, TE=512, TD=256, H=256, fp32.
//   We = enc @ W_a; Uh = dec @ U_a
//   e[b,j,i] = softmax_i( sum_h V[h]*tanh(We[b,i,h]+Uh[b,j,h]) )
//   c[b,j,h] = sum_i e[b,j,i]*enc[b,i,h]
// d_out = [c (B*TD*H)] ++ [e (B*TD*TE)]
//
// R20 (this round): REGISTER-RESIDENT u/v. R19's accident (SGPR 112->32,
// 66us) + R12 (LDS path 43us) + baseline (SMEM path 39.5us @50% busy)
// prove phase A's stall is the u/v BROADCAST DELIVERY through shared
// per-CU resources (sK$/LDS/L1), ~20us of the 39.5. Fix: slice h across
// the 16 lanes of each i-subgroup (lane = i_idx*16 + h_grp; lane's h =
// q*64 + h_grp*4). u (4j x 4quads = 64 VGPR) + v (16 VGPR) are loaded
// ONCE per block, coalesced; the loop is {4 coalesced w4 loads + 208
// VALU + 16 rcp} per 4-i iteration -- no SMEM, no LDS. Per-i energy via
// 4-step shfl_xor butterfly (within the 16-lane group). W4/Uhe now plain
// row-major -> k_pre epilogue is ONE unconditional store (enc|dec rows
// contiguous). Reduction order changes (tree) -> absmax ~5e-4 still.
// R15 keeps: 2-kernel config, fused weight-transpose k_pre.
// R11 keeps: 2-deep enc prefetch (phase B). R9: split-bf16 MFMA.
// R8: 4-way rcp batching. R7: XCD swizzle (b = blockIdx&7).

#define BB 8
#define TE 512
#define TD 256
#define HH 256

#define EXP2F(x) __builtin_amdgcn_exp2f(x)
#define RCPF(x)  __builtin_amdgcn_rcpf(x)
#define KSCALE   2.8853900817779268f    // 2*log2(e)
#define NSC      (-2.8853900817779268f) // -2*log2(e)

typedef __attribute__((ext_vector_type(8))) short short8_t;  // 8 bf16 = 4 VGPR
typedef __attribute__((ext_vector_type(4))) float f32x4;     // MFMA acc

__device__ __forceinline__ unsigned short f2bf(float x) {
    unsigned int u = __float_as_uint(x);
    return (unsigned short)((u + 0x7FFFu + ((u >> 16) & 1u)) >> 16);  // RNE
}
__device__ __forceinline__ float bf2f(unsigned short h) {
    return __uint_as_float(((unsigned int)h) << 16);
}

// ---------------------------------------------------------------------------
// k_pre (R20): split-bf16 MFMA GEMM over X = [enc; dec], D[h][i], fused
// weight transpose (R15 body). Epilogue simplified: outputs are plain
// row-major exp2-domain rows, enc rows [0,4096) then dec rows [4096,6144)
// contiguous in one buffer -> ONE unconditional float4 store per frag.
// Fragment layouts (m89-verified):
//   A/B frags: row/col = l&15, k-octet = (l>>4)*8; D: col=l&15, row=(l>>4)*4+reg.
// ---------------------------------------------------------------------------
__global__ __launch_bounds__(256) void k_pre(
    const float* __restrict__ enc, const float* __restrict__ dec,
    const float* __restrict__ Wa,  const float* __restrict__ Ua,
    float* __restrict__ Wout)
{
    const int t  = threadIdx.x;
    const int it = blockIdx.x >> 2;       // 0..95  (i-tile)
    const int ht = blockIdx.x & 3;        // 0..3   (h-tile)
    const int i0 = it * 64;
    const int h0 = ht * 64;
    const bool is_enc = (i0 < BB * TE);   // < 4096
    const float* X  = is_enc ? (enc + (size_t)i0 * HH)
                             : (dec + (size_t)(i0 - BB * TE) * HH);
    const float* Wg = is_enc ? Wa : Ua;

    __shared__ unsigned short At_h[64][40], At_l[64][40];
    __shared__ unsigned short Xs_h[64][40], Xs_l[64][40];
    __shared__ float T[32][66];           // fp32 W chunk, padded

    const int sr = t >> 2;                // X staging row / At pass-2 h (0..63)
    const int sq = (t & 3) * 8;           // k-octet (0,8,16,24)
    const int kr = t >> 3;                // W load k-row (0..31)
    const int hc = (t & 7) * 8;           // W load h-base (0..56)

    const int wv = t >> 6, l = t & 63;
    const int wh = (wv & 1) * 32;
    const int wi = (wv >> 1) * 32;
    const int fr = l & 15;
    const int fk = (l >> 4) * 8;
    const int rq = l >> 4;                // D row-quad

    f32x4 acc[2][2];
    #pragma unroll
    for (int a0 = 0; a0 < 2; a0++)
        #pragma unroll
        for (int a1 = 0; a1 < 2; a1++)
            acc[a0][a1] = (f32x4){0.f, 0.f, 0.f, 0.f};

    float4 x0  = *(const float4*)(X + (size_t)sr * HH + sq);
    float4 x1  = *(const float4*)(X + (size_t)sr * HH + sq + 4);
    float4 wf0 = *(const float4*)(Wg + (size_t)kr * HH + h0 + hc);
    float4 wf1 = *(const float4*)(Wg + (size_t)kr * HH + h0 + hc + 4);

    #pragma unroll
    for (int c = 0; c < 8; c++) {
        short8_t xh, xl;
        {
            unsigned short h;
            h = f2bf(x0.x); xh[0] = (short)h; xl[0] = (short)f2bf(x0.x - bf2f(h));
            h = f2bf(x0.y); xh[1] = (short)h; xl[1] = (short)f2bf(x0.y - bf2f(h));
            h = f2bf(x0.z); xh[2] = (short)h; xl[2] = (short)f2bf(x0.z - bf2f(h));
            h = f2bf(x0.w); xh[3] = (short)h; xl[3] = (short)f2bf(x0.w - bf2f(h));
            h = f2bf(x1.x); xh[4] = (short)h; xl[4] = (short)f2bf(x1.x - bf2f(h));
            h = f2bf(x1.y); xh[5] = (short)h; xl[5] = (short)f2bf(x1.y - bf2f(h));
            h = f2bf(x1.z); xh[6] = (short)h; xl[6] = (short)f2bf(x1.z - bf2f(h));
            h = f2bf(x1.w); xh[7] = (short)h; xl[7] = (short)f2bf(x1.w - bf2f(h));
        }
        __syncthreads();   // B1: prior chunk's MFMA readers done
        *(short8_t*)&Xs_h[sr][sq] = xh;
        *(short8_t*)&Xs_l[sr][sq] = xl;
        {
            float2 a, b;
            a.x = wf0.x; a.y = wf0.y; b.x = wf0.z; b.y = wf0.w;
            *(float2*)&T[kr][hc]     = a;
            *(float2*)&T[kr][hc + 2] = b;
            a.x = wf1.x; a.y = wf1.y; b.x = wf1.z; b.y = wf1.w;
            *(float2*)&T[kr][hc + 4] = a;
            *(float2*)&T[kr][hc + 6] = b;
        }
        __syncthreads();   // B2: T + Xs ready
        {
            short8_t ah_, al_;
            #pragma unroll
            for (int e = 0; e < 8; e++) {
                float f = T[sq + e][sr];
                unsigned short h = f2bf(f);
                ah_[e] = (short)h;
                al_[e] = (short)f2bf(f - bf2f(h));
            }
            *(short8_t*)&At_h[sr][sq] = ah_;
            *(short8_t*)&At_l[sr][sq] = al_;
        }
        if (c < 7) {
            const int kc = (c + 1) * 32;
            x0  = *(const float4*)(X + (size_t)sr * HH + kc + sq);
            x1  = *(const float4*)(X + (size_t)sr * HH + kc + sq + 4);
            wf0 = *(const float4*)(Wg + (size_t)(kc + kr) * HH + h0 + hc);
            wf1 = *(const float4*)(Wg + (size_t)(kc + kr) * HH + h0 + hc + 4);
        }
        __syncthreads();   // B3: At ready
        #pragma unroll
        for (int fm = 0; fm < 2; fm++) {
            short8_t a_h = *(const short8_t*)&At_h[wh + 16 * fm + fr][fk];
            short8_t a_l = *(const short8_t*)&At_l[wh + 16 * fm + fr][fk];
            #pragma unroll
            for (int fn = 0; fn < 2; fn++) {
                short8_t b_h = *(const short8_t*)&Xs_h[wi + 16 * fn + fr][fk];
                short8_t b_l = *(const short8_t*)&Xs_l[wi + 16 * fn + fr][fk];
                acc[fm][fn] = __builtin_amdgcn_mfma_f32_16x16x32_bf16(a_h, b_h, acc[fm][fn], 0, 0, 0);
                acc[fm][fn] = __builtin_amdgcn_mfma_f32_16x16x32_bf16(a_h, b_l, acc[fm][fn], 0, 0, 0);
                acc[fm][fn] = __builtin_amdgcn_mfma_f32_16x16x32_bf16(a_l, b_h, acc[fm][fn], 0, 0, 0);
            }
        }
    }

    #pragma unroll
    for (int fm = 0; fm < 2; fm++) {
        #pragma unroll
        for (int fn = 0; fn < 2; fn++) {
            f32x4 v = acc[fm][fn];
            float4 o;
            o.x = EXP2F(v[0] * KSCALE);
            o.y = EXP2F(v[1] * KSCALE);
            o.z = EXP2F(v[2] * KSCALE);
            o.w = EXP2F(v[3] * KSCALE);
            const int ig = i0 + wi + 16 * fn + fr;      // global concat row
            const int hb = h0 + wh + 16 * fm + rq * 4;  // 4 consecutive h
            *(float4*)(Wout + (size_t)ig * HH + hb) = o;  // row-major, one path
        }
    }
}

// ---------------------------------------------------------------------------
// k_attn (R20): 512 threads = 8 waves; block owns 4 consecutive j's of ONE
// batch, batch = blockIdx&7 (XCD-local).
// Phase A re-sliced: lane = i_idx*16 + h_grp (i_idx = lane>>4, h_grp =
// lane&15); lane's h set = {q*64 + h_grp*4 ..+3, q=0..3}. u (4j x 4q) and
// v (4q) live in REGISTERS, loaded once, coalesced. Loop over 16 its x
// 4 i: 4 coalesced w4 float4 loads + 16 QSTEPs; butterfly shfl_xor
// (1,2,4,8) reduces over h_grp; lanes h_grp<4 write sP[h_grp][i].
// Softmax: waves 0-3 (unchanged). Phase B: unchanged (R11 enc prefetch).
// ---------------------------------------------------------------------------
__global__ __launch_bounds__(512) void k_attn(
    const float* __restrict__ enc, const float* __restrict__ W4r,
    const float* __restrict__ Uhe, const float* __restrict__ Va,
    float* __restrict__ out_c, float* __restrict__ out_e)
{
    const int wv = threadIdx.x >> 6, lane = threadIdx.x & 63;
    const int b   = blockIdx.x & 7;           // XCD-local batch
    const int j0  = (blockIdx.x >> 3) * 4;    // 64 j-groups per batch
    const int jj0 = b * TD + j0;              // block-uniform
    const int ig  = lane >> 4;                // i-sub 0..3
    const int hg  = lane & 15;                // h-group 0..15

    __shared__ float sP[4][TE];      // 8 KB: energies -> probabilities
    __shared__ float sR[8][4][HH];   // 32 KB: phase-B partials

    // ---- load u (4j x 4 quads) + v (4 quads) into registers, coalesced --
    const float* ua = Uhe + (size_t)jj0 * HH + hg * 4;
    const float* va = Va + hg * 4;
    float4 v0 = *(const float4*)(va);
    float4 v1 = *(const float4*)(va + 64);
    float4 v2 = *(const float4*)(va + 128);
    float4 v3 = *(const float4*)(va + 192);
    float4 u00 = *(const float4*)(ua);
    float4 u01 = *(const float4*)(ua + 64);
    float4 u02 = *(const float4*)(ua + 128);
    float4 u03 = *(const float4*)(ua + 192);
    float4 u10 = *(const float4*)(ua + HH);
    float4 u11 = *(const float4*)(ua + HH + 64);
    float4 u12 = *(const float4*)(ua + HH + 128);
    float4 u13 = *(const float4*)(ua + HH + 192);
    float4 u20 = *(const float4*)(ua + 2 * HH);
    float4 u21 = *(const float4*)(ua + 2 * HH + 64);
    float4 u22 = *(const float4*)(ua + 2 * HH + 128);
    float4 u23 = *(const float4*)(ua + 2 * HH + 192);
    float4 u30 = *(const float4*)(ua + 3 * HH);
    float4 u31 = *(const float4*)(ua + 3 * HH + 64);
    float4 u32 = *(const float4*)(ua + 3 * HH + 128);
    float4 u33 = *(const float4*)(ua + 3 * HH + 192);

    // w4 row base for this lane: its i-sub within the wave's 64-i range
    const float* wp = W4r + ((size_t)(b * TE) + (wv << 6) + ig) * HH + hg * 4;

    // 4-way batched reciprocal:
    //   sum_k v_k/A_k = (nAB*dCD + nCD*dAB) / (dAB*dCD)
#define QSTEP(ACC, WQ, VQ, UQ)                                            \
    {                                                                     \
        float A_ = fmaf((WQ).x, (UQ).x, 1.f);                             \
        float B_ = fmaf((WQ).y, (UQ).y, 1.f);                             \
        float C_ = fmaf((WQ).z, (UQ).z, 1.f);                             \
        float D_ = fmaf((WQ).w, (UQ).w, 1.f);                             \
        float dAB = A_ * B_, dCD = C_ * D_;                               \
        float nAB = fmaf((VQ).x, B_, (VQ).y * A_);                        \
        float nCD = fmaf((VQ).z, D_, (VQ).w * C_);                        \
        float num = fmaf(nAB, dCD, nCD * dAB);                            \
        ACC = fmaf(num, RCPF(dAB * dCD), ACC);                            \
    }

    #pragma unroll 2
    for (int it = 0; it < 16; it++) {
        const float* wrow = wp + (size_t)(it << 2) * HH;
        float4 w0 = *(const float4*)(wrow);
        float4 w1 = *(const float4*)(wrow + 64);
        float4 w2 = *(const float4*)(wrow + 128);
        float4 w3 = *(const float4*)(wrow + 192);
        float a0 = 0.f, a1 = 0.f, a2 = 0.f, a3 = 0.f;
        QSTEP(a0, w0, v0, u00) QSTEP(a0, w1, v1, u01)
        QSTEP(a0, w2, v2, u02) QSTEP(a0, w3, v3, u03)
        QSTEP(a1, w0, v0, u10) QSTEP(a1, w1, v1, u11)
        QSTEP(a1, w2, v2, u12) QSTEP(a1, w3, v3, u13)
        QSTEP(a2, w0, v0, u20) QSTEP(a2, w1, v1, u21)
        QSTEP(a2, w2, v2, u22) QSTEP(a2, w3, v3, u23)
        QSTEP(a3, w0, v0, u30) QSTEP(a3, w1, v1, u31)
        QSTEP(a3, w2, v2, u32) QSTEP(a3, w3, v3, u33)
        // butterfly reduce over the 16 h-groups (masks stay in bits 0..3)
        #pragma unroll
        for (int off = 1; off <= 8; off <<= 1) {
            a0 += __shfl_xor(a0, off, 64);
            a1 += __shfl_xor(a1, off, 64);
            a2 += __shfl_xor(a2, off, 64);
            a3 += __shfl_xor(a3, off, 64);
        }
        float outv = hg == 0 ? a0 : (hg == 1 ? a1 : (hg == 2 ? a2 : a3));
        if (hg < 4) sP[hg][(wv << 6) + (it << 2) + ig] = NSC * outv;
    }
#undef QSTEP
    __syncthreads();

    // ---- softmax: wave w in 0..3 handles j0+w ----------------------------
    if (wv < 4) {
        float ev[8];
        float m = -3.0e38f;
        #pragma unroll
        for (int k = 0; k < 8; k++) {
            ev[k] = sP[wv][lane + 64 * k];
            m = fmaxf(m, ev[k]);
        }
        #pragma unroll
        for (int off = 32; off; off >>= 1) m = fmaxf(m, __shfl_xor(m, off, 64));
        float s = 0.f;
        #pragma unroll
        for (int k = 0; k < 8; k++) { ev[k] = EXP2F(ev[k] - m); s += ev[k]; }
        #pragma unroll
        for (int off = 32; off; off >>= 1) s += __shfl_xor(s, off, 64);
        float rs = RCPF(s);
        float* oe = out_e + (size_t)(jj0 + wv) * TE;
        #pragma unroll
        for (int k = 0; k < 8; k++) {
            float p = ev[k] * rs;
            sP[wv][lane + 64 * k] = p;
            oe[lane + 64 * k] = p;
        }
    }
    __syncthreads();

    // ---- Phase B: wave w -> i in [64w, 64w+64), all 4 j ------------------
    const int ib = wv << 6;
    const float* eb = enc + ((size_t)b * TE + ib) * HH + 4 * lane;
    float4 c0 = {0,0,0,0}, c1 = {0,0,0,0}, c2 = {0,0,0,0}, c3 = {0,0,0,0};

#define BSTEP(K, QV)                                                      \
    {                                                                     \
        float p0 = sP[0][ib + (K)];                                       \
        float p1 = sP[1][ib + (K)];                                       \
        float p2 = sP[2][ib + (K)];                                       \
        float p3 = sP[3][ib + (K)];                                       \
        float4 q = QV;                                                    \
        c0.x = fmaf(p0, q.x, c0.x); c0.y = fmaf(p0, q.y, c0.y);           \
        c0.z = fmaf(p0, q.z, c0.z); c0.w = fmaf(p0, q.w, c0.w);           \
        c1.x = fmaf(p1, q.x, c1.x); c1.y = fmaf(p1, q.y, c1.y);           \
        c1.z = fmaf(p1, q.z, c1.z); c1.w = fmaf(p1, q.w, c1.w);           \
        c2.x = fmaf(p2, q.x, c2.x); c2.y = fmaf(p2, q.y, c2.y);           \
        c2.z = fmaf(p2, q.z, c2.z); c2.w = fmaf(p2, q.w, c2.w);           \
        c3.x = fmaf(p3, q.x, c3.x); c3.y = fmaf(p3, q.y, c3.y);           \
        c3.z = fmaf(p3, q.z, c3.z); c3.w = fmaf(p3, q.w, c3.w);           \
    }

    // 2-deep software pipeline on the per-lane enc stream (tail clamped:
    // enc is an input buffer, no OOB reads allowed)
    float4 qA = *(const float4*)(eb);
    float4 qB = *(const float4*)(eb + (size_t)HH);
    for (int k = 0; k < 64; k += 2) {
        const int k2 = (k + 2 < 64) ? k + 2 : 62;
        const int k3 = (k + 3 < 64) ? k + 3 : 63;
        float4 qC = *(const float4*)(eb + (size_t)k2 * HH);
        float4 qD = *(const float4*)(eb + (size_t)k3 * HH);
        BSTEP(k, qA)
        BSTEP(k + 1, qB)
        qA = qC; qB = qD;
    }
#undef BSTEP

    *(float4*)&sR[wv][0][4 * lane] = c0;
    *(float4*)&sR[wv][1][4 * lane] = c1;
    *(float4*)&sR[wv][2][4 * lane] = c2;
    *(float4*)&sR[wv][3][4 * lane] = c3;
    __syncthreads();

    // ---- final reduce: wave w -> (j = w&3, h-half = w>>2) ----------------
    {
        const int jr = wv & 3;
        const int h2 = (wv >> 2) * 128 + 2 * lane;
        float sx = 0.f, sy = 0.f;
        #pragma unroll
        for (int ww = 0; ww < 8; ww++) {
            float2 tv = *(const float2*)&sR[ww][jr][h2];
            sx += tv.x; sy += tv.y;
        }
        float2 o; o.x = sx; o.y = sy;
        *(float2*)(out_c + (size_t)(jj0 + jr) * HH + h2) = o;
    }
}

extern "C" void kernel_launch(void* const* d_in, const int* in_sizes, int n_in,
                              void* d_out, int out_size, void* d_ws, size_t ws_size,
                              hipStream_t stream) {
    const float* enc = (const float*)d_in[0];
    const float* dec = (const float*)d_in[1];
    const float* Wa  = (const float*)d_in[2];
    const float* Ua  = (const float*)d_in[3];
    const float* Va  = (const float*)d_in[4];

    float* Wout = (float*)d_ws;                        // exp2-domain rows, 6144x256
    float* W4r  = Wout;                                // enc rows [0,4096)
    float* Uhe  = Wout + (size_t)BB * TE * HH;         // dec rows [4096,6144)

    float* out_c = (float*)d_out;                      // [B,TD,H]
    float* out_e = out_c + (size_t)BB * TD * HH;       // [B,TD,TE]

    k_pre<<<384, 256, 0, stream>>>(enc, dec, Wa, Ua, Wout);
    k_attn<<<BB * TD / 4, 512, 0, stream>>>(enc, W4r, Uhe, Va, out_c, out_e);
}

// Round 13
// 106.580 us; speedup vs baseline: 1.2335x; 1.1074x over previous
//
#include <hip/hip_runtime.h>

// Bahdanau additive attention: B=8, TE=512, TD=256, H=256, fp32.
//   We = enc @ W_a; Uh = dec @ U_a
//   e[b,j,i] = softmax_i( sum_h V[h]*tanh(We[b,i,h]+Uh[b,j,h]) )
//   c[b,j,h] = sum_i e[b,j,i]*enc[b,i,h]
// d_out = [c (B*TD*H)] ++ [e (B*TD*TE)]
//
// R21 (this round): FP16 W4 -- the last unisolated mechanism. 12 rounds
// eliminated every scheduling/delivery lever for phase A's ~50% stall;
// the one resource never cleanly tested is vector-memory BYTES (R17's
// traffic-halving was confounded with occupancy loss). This round halves
// the w-stream bytes (268->134MB) with zero other changes: W4 stored as
// fp16 (rel err 2^-12; w~=exp2(K*We) in [2^-16,2^16] at 12sigma -> no
// overflow; energy perturbation ~1e-4 -> absmax ~5-7e-4, passes).
// Phase A: ushort4 load (8B/lane) + 4 v_cvt_f32_f16 per q (+7% VALU).
// If null -> plateau declared next round with the full ledger.
// R15 keeps: 2-kernel config, fused weight-transpose k_pre.
// R11 keeps: 2-deep named-reg prefetch (w, enc). R9: split-bf16 MFMA.
// R8: 4-way rcp batching. R7: XCD swizzle (b = blockIdx&7), W4 layout.

#define BB 8
#define TE 512
#define TD 256
#define HH 256

#define EXP2F(x) __builtin_amdgcn_exp2f(x)
#define RCPF(x)  __builtin_amdgcn_rcpf(x)
#define KSCALE   2.8853900817779268f    // 2*log2(e)
#define NSC      (-2.8853900817779268f) // -2*log2(e)

typedef __attribute__((ext_vector_type(8))) short short8_t;  // 8 bf16 = 4 VGPR
typedef __attribute__((ext_vector_type(4))) float f32x4;     // MFMA acc

__device__ __forceinline__ unsigned short f2bf(float x) {
    unsigned int u = __float_as_uint(x);
    return (unsigned short)((u + 0x7FFFu + ((u >> 16) & 1u)) >> 16);  // RNE
}
__device__ __forceinline__ float bf2f(unsigned short h) {
    return __uint_as_float(((unsigned int)h) << 16);
}
__device__ __forceinline__ unsigned short f2h(float x) {   // v_cvt_f16_f32
    _Float16 h = (_Float16)x;
    unsigned short u;
    __builtin_memcpy(&u, &h, 2);
    return u;
}
__device__ __forceinline__ float h2f(unsigned short u) {   // v_cvt_f32_f16
    _Float16 h;
    __builtin_memcpy(&h, &u, 2);
    return (float)h;
}

// ---------------------------------------------------------------------------
// k_pre (R21): split-bf16 MFMA GEMM over X = [enc; dec], D[h][i], fused
// weight transpose (R15 body). Enc epilogue now stores fp16 quads (8B)
// into W4h[b][hq][i][4]; dec epilogue unchanged (fp32 Uhe rows).
// Fragment layouts (m89-verified):
//   A/B frags: row/col = l&15, k-octet = (l>>4)*8; D: col=l&15, row=(l>>4)*4+reg.
// ---------------------------------------------------------------------------
__global__ __launch_bounds__(256) void k_pre(
    const float* __restrict__ enc, const float* __restrict__ dec,
    const float* __restrict__ Wa,  const float* __restrict__ Ua,
    unsigned short* __restrict__ W4h, float* __restrict__ Uhe)
{
    const int t  = threadIdx.x;
    const int it = blockIdx.x >> 2;       // 0..95  (i-tile)
    const int ht = blockIdx.x & 3;        // 0..3   (h-tile)
    const int i0 = it * 64;
    const int h0 = ht * 64;
    const bool is_enc = (i0 < BB * TE);   // < 4096
    const float* X  = is_enc ? (enc + (size_t)i0 * HH)
                             : (dec + (size_t)(i0 - BB * TE) * HH);
    const float* Wg = is_enc ? Wa : Ua;

    __shared__ unsigned short At_h[64][40], At_l[64][40];
    __shared__ unsigned short Xs_h[64][40], Xs_l[64][40];
    __shared__ float T[32][66];           // fp32 W chunk, padded

    const int sr = t >> 2;                // X staging row / At pass-2 h (0..63)
    const int sq = (t & 3) * 8;           // k-octet (0,8,16,24)
    const int kr = t >> 3;                // W load k-row (0..31)
    const int hc = (t & 7) * 8;           // W load h-base (0..56)

    const int wv = t >> 6, l = t & 63;
    const int wh = (wv & 1) * 32;
    const int wi = (wv >> 1) * 32;
    const int fr = l & 15;
    const int fk = (l >> 4) * 8;
    const int rq = l >> 4;                // D row-quad

    f32x4 acc[2][2];
    #pragma unroll
    for (int a0 = 0; a0 < 2; a0++)
        #pragma unroll
        for (int a1 = 0; a1 < 2; a1++)
            acc[a0][a1] = (f32x4){0.f, 0.f, 0.f, 0.f};

    float4 x0  = *(const float4*)(X + (size_t)sr * HH + sq);
    float4 x1  = *(const float4*)(X + (size_t)sr * HH + sq + 4);
    float4 wf0 = *(const float4*)(Wg + (size_t)kr * HH + h0 + hc);
    float4 wf1 = *(const float4*)(Wg + (size_t)kr * HH + h0 + hc + 4);

    #pragma unroll
    for (int c = 0; c < 8; c++) {
        short8_t xh, xl;
        {
            unsigned short h;
            h = f2bf(x0.x); xh[0] = (short)h; xl[0] = (short)f2bf(x0.x - bf2f(h));
            h = f2bf(x0.y); xh[1] = (short)h; xl[1] = (short)f2bf(x0.y - bf2f(h));
            h = f2bf(x0.z); xh[2] = (short)h; xl[2] = (short)f2bf(x0.z - bf2f(h));
            h = f2bf(x0.w); xh[3] = (short)h; xl[3] = (short)f2bf(x0.w - bf2f(h));
            h = f2bf(x1.x); xh[4] = (short)h; xl[4] = (short)f2bf(x1.x - bf2f(h));
            h = f2bf(x1.y); xh[5] = (short)h; xl[5] = (short)f2bf(x1.y - bf2f(h));
            h = f2bf(x1.z); xh[6] = (short)h; xl[6] = (short)f2bf(x1.z - bf2f(h));
            h = f2bf(x1.w); xh[7] = (short)h; xl[7] = (short)f2bf(x1.w - bf2f(h));
        }
        __syncthreads();   // B1: prior chunk's MFMA readers done
        *(short8_t*)&Xs_h[sr][sq] = xh;
        *(short8_t*)&Xs_l[sr][sq] = xl;
        {
            float2 a, b;
            a.x = wf0.x; a.y = wf0.y; b.x = wf0.z; b.y = wf0.w;
            *(float2*)&T[kr][hc]     = a;
            *(float2*)&T[kr][hc + 2] = b;
            a.x = wf1.x; a.y = wf1.y; b.x = wf1.z; b.y = wf1.w;
            *(float2*)&T[kr][hc + 4] = a;
            *(float2*)&T[kr][hc + 6] = b;
        }
        __syncthreads();   // B2: T + Xs ready
        {
            short8_t ah_, al_;
            #pragma unroll
            for (int e = 0; e < 8; e++) {
                float f = T[sq + e][sr];
                unsigned short h = f2bf(f);
                ah_[e] = (short)h;
                al_[e] = (short)f2bf(f - bf2f(h));
            }
            *(short8_t*)&At_h[sr][sq] = ah_;
            *(short8_t*)&At_l[sr][sq] = al_;
        }
        if (c < 7) {
            const int kc = (c + 1) * 32;
            x0  = *(const float4*)(X + (size_t)sr * HH + kc + sq);
            x1  = *(const float4*)(X + (size_t)sr * HH + kc + sq + 4);
            wf0 = *(const float4*)(Wg + (size_t)(kc + kr) * HH + h0 + hc);
            wf1 = *(const float4*)(Wg + (size_t)(kc + kr) * HH + h0 + hc + 4);
        }
        __syncthreads();   // B3: At ready
        #pragma unroll
        for (int fm = 0; fm < 2; fm++) {
            short8_t a_h = *(const short8_t*)&At_h[wh + 16 * fm + fr][fk];
            short8_t a_l = *(const short8_t*)&At_l[wh + 16 * fm + fr][fk];
            #pragma unroll
            for (int fn = 0; fn < 2; fn++) {
                short8_t b_h = *(const short8_t*)&Xs_h[wi + 16 * fn + fr][fk];
                short8_t b_l = *(const short8_t*)&Xs_l[wi + 16 * fn + fr][fk];
                acc[fm][fn] = __builtin_amdgcn_mfma_f32_16x16x32_bf16(a_h, b_h, acc[fm][fn], 0, 0, 0);
                acc[fm][fn] = __builtin_amdgcn_mfma_f32_16x16x32_bf16(a_h, b_l, acc[fm][fn], 0, 0, 0);
                acc[fm][fn] = __builtin_amdgcn_mfma_f32_16x16x32_bf16(a_l, b_h, acc[fm][fn], 0, 0, 0);
            }
        }
    }

    #pragma unroll
    for (int fm = 0; fm < 2; fm++) {
        #pragma unroll
        for (int fn = 0; fn < 2; fn++) {
            f32x4 v = acc[fm][fn];
            float4 o;
            o.x = EXP2F(v[0] * KSCALE);
            o.y = EXP2F(v[1] * KSCALE);
            o.z = EXP2F(v[2] * KSCALE);
            o.w = EXP2F(v[3] * KSCALE);
            const int ig = i0 + wi + 16 * fn + fr;      // global concat row
            const int hb = h0 + wh + 16 * fm + rq * 4;  // 4 consecutive h
            if (is_enc) {
                const int b  = ig >> 9;                 // 512 enc rows per batch
                const int ib = ig & 511;
                const int hq = hb >> 2;
                ushort4 oh;
                oh.x = f2h(o.x); oh.y = f2h(o.y);
                oh.z = f2h(o.z); oh.w = f2h(o.w);
                *(ushort4*)(W4h + (((size_t)b * 64 + hq) * TE + ib) * 4) = oh;
            } else {
                const int j = ig - BB * TE;             // global dec row
                *(float4*)(Uhe + (size_t)j * HH + hb) = o;
            }
        }
    }
}

// ---------------------------------------------------------------------------
// k_attn (R21): 512 threads = 8 waves; block owns 4 consecutive j's of ONE
// batch, batch = blockIdx&7 (XCD-local).
// Phase A: wave w -> i = 64w+lane; w-stream is fp16 quads (ushort4, 8B per
// lane-load -- HALF the bytes of the fp32 form), 2-deep named-reg prefetch,
// 4 cvt_f32_f16 per q. u/v stay fp32 uniform s_loads (unchanged path).
// OOB prefetch at q=62 lands in the adjacent Uhe region (safe, unused).
// Softmax: waves 0-3. Phase B: 2-deep prefetch on the enc stream.
// ---------------------------------------------------------------------------
__global__ __launch_bounds__(512) void k_attn(
    const float* __restrict__ enc, const unsigned short* __restrict__ W4h,
    const float* __restrict__ Uhe, const float* __restrict__ Va,
    float* __restrict__ out_c, float* __restrict__ out_e)
{
    const int wv = threadIdx.x >> 6, lane = threadIdx.x & 63;
    const int b   = blockIdx.x & 7;           // XCD-local batch
    const int j0  = (blockIdx.x >> 3) * 4;    // 64 j-groups per batch
    const int jj0 = b * TD + j0;              // block-uniform

    __shared__ float sP[4][TE];      // 8 KB: energies -> probabilities
    __shared__ float sR[8][4][HH];   // 32 KB: phase-B partials

    const int i = (wv << 6) + lane;
    const unsigned short* wp = W4h + ((size_t)b * 64 * TE + i) * 4;
    const float* ua = Uhe + (size_t)jj0 * HH;   // block-uniform -> s_load
    const float* va = Va;                        // uniform

    float a0 = 0.f, a1 = 0.f, a2 = 0.f, a3 = 0.f;

    // 4-way batched reciprocal:
    //   sum_k v_k/A_k = (nAB*dCD + nCD*dAB) / (dAB*dCD)
#define QSTEP(ACC, U)                                                     \
    {                                                                     \
        float A_ = fmaf(w4.x, (U).x, 1.f);                                \
        float B_ = fmaf(w4.y, (U).y, 1.f);                                \
        float C_ = fmaf(w4.z, (U).z, 1.f);                                \
        float D_ = fmaf(w4.w, (U).w, 1.f);                                \
        float dAB = A_ * B_, dCD = C_ * D_;                               \
        float nAB = fmaf(v4.x, B_, v4.y * A_);                            \
        float nCD = fmaf(v4.z, D_, v4.w * C_);                            \
        float num = fmaf(nAB, dCD, nCD * dAB);                            \
        ACC = fmaf(num, RCPF(dAB * dCD), ACC);                            \
    }

#define ASTEP(Q, WH)                                                      \
    {                                                                     \
        float4 w4;                                                        \
        w4.x = h2f((WH).x); w4.y = h2f((WH).y);                           \
        w4.z = h2f((WH).z); w4.w = h2f((WH).w);                           \
        float4 v4 = *(const float4*)(va + 4 * (Q));                       \
        float4 u0 = *(const float4*)(ua + 4 * (Q));                       \
        float4 u1 = *(const float4*)(ua + HH + 4 * (Q));                  \
        float4 u2 = *(const float4*)(ua + 2 * HH + 4 * (Q));              \
        float4 u3 = *(const float4*)(ua + 3 * HH + 4 * (Q));              \
        QSTEP(a0, u0)                                                     \
        QSTEP(a1, u1)                                                     \
        QSTEP(a2, u2)                                                     \
        QSTEP(a3, u3)                                                     \
    }

    // 2-deep software pipeline on the per-lane fp16 w-stream
    ushort4 wA = *(const ushort4*)(wp);
    ushort4 wB = *(const ushort4*)(wp + (size_t)TE * 4);
    for (int q = 0; q < 64; q += 2) {
        ushort4 wC = *(const ushort4*)(wp + (size_t)(q + 2) * TE * 4);
        ushort4 wD = *(const ushort4*)(wp + (size_t)(q + 3) * TE * 4);
        ASTEP(q, wA)
        ASTEP(q + 1, wB)
        wA = wC; wB = wD;
    }
#undef ASTEP
#undef QSTEP

    // conflict-free b32 writes (lane-stride 4B), energies in log2 domain
    sP[0][i] = NSC * a0;
    sP[1][i] = NSC * a1;
    sP[2][i] = NSC * a2;
    sP[3][i] = NSC * a3;
    __syncthreads();

    // ---- softmax: wave w in 0..3 handles j0+w ----------------------------
    if (wv < 4) {
        float ev[8];
        float m = -3.0e38f;
        #pragma unroll
        for (int k = 0; k < 8; k++) {
            ev[k] = sP[wv][lane + 64 * k];
            m = fmaxf(m, ev[k]);
        }
        #pragma unroll
        for (int off = 32; off; off >>= 1) m = fmaxf(m, __shfl_xor(m, off, 64));
        float s = 0.f;
        #pragma unroll
        for (int k = 0; k < 8; k++) { ev[k] = EXP2F(ev[k] - m); s += ev[k]; }
        #pragma unroll
        for (int off = 32; off; off >>= 1) s += __shfl_xor(s, off, 64);
        float rs = RCPF(s);
        float* oe = out_e + (size_t)(jj0 + wv) * TE;
        #pragma unroll
        for (int k = 0; k < 8; k++) {
            float p = ev[k] * rs;
            sP[wv][lane + 64 * k] = p;
            oe[lane + 64 * k] = p;
        }
    }
    __syncthreads();

    // ---- Phase B: wave w -> i in [64w, 64w+64), all 4 j ------------------
    const int ib = wv << 6;
    const float* eb = enc + ((size_t)b * TE + ib) * HH + 4 * lane;
    float4 c0 = {0,0,0,0}, c1 = {0,0,0,0}, c2 = {0,0,0,0}, c3 = {0,0,0,0};

#define BSTEP(K, QV)                                                      \
    {                                                                     \
        float p0 = sP[0][ib + (K)];                                       \
        float p1 = sP[1][ib + (K)];                                       \
        float p2 = sP[2][ib + (K)];                                       \
        float p3 = sP[3][ib + (K)];                                       \
        float4 q = QV;                                                    \
        c0.x = fmaf(p0, q.x, c0.x); c0.y = fmaf(p0, q.y, c0.y);           \
        c0.z = fmaf(p0, q.z, c0.z); c0.w = fmaf(p0, q.w, c0.w);           \
        c1.x = fmaf(p1, q.x, c1.x); c1.y = fmaf(p1, q.y, c1.y);           \
        c1.z = fmaf(p1, q.z, c1.z); c1.w = fmaf(p1, q.w, c1.w);           \
        c2.x = fmaf(p2, q.x, c2.x); c2.y = fmaf(p2, q.y, c2.y);           \
        c2.z = fmaf(p2, q.z, c2.z); c2.w = fmaf(p2, q.w, c2.w);           \
        c3.x = fmaf(p3, q.x, c3.x); c3.y = fmaf(p3, q.y, c3.y);           \
        c3.z = fmaf(p3, q.z, c3.z); c3.w = fmaf(p3, q.w, c3.w);           \
    }

    // 2-deep software pipeline on the per-lane enc stream (tail clamped:
    // enc is an input buffer, no OOB reads allowed)
    float4 qA = *(const float4*)(eb);
    float4 qB = *(const float4*)(eb + (size_t)HH);
    for (int k = 0; k < 64; k += 2) {
        const int k2 = (k + 2 < 64) ? k + 2 : 62;
        const int k3 = (k + 3 < 64) ? k + 3 : 63;
        float4 qC = *(const float4*)(eb + (size_t)k2 * HH);
        float4 qD = *(const float4*)(eb + (size_t)k3 * HH);
        BSTEP(k, qA)
        BSTEP(k + 1, qB)
        qA = qC; qB = qD;
    }
#undef BSTEP

    *(float4*)&sR[wv][0][4 * lane] = c0;
    *(float4*)&sR[wv][1][4 * lane] = c1;
    *(float4*)&sR[wv][2][4 * lane] = c2;
    *(float4*)&sR[wv][3][4 * lane] = c3;
    __syncthreads();

    // ---- final reduce: wave w -> (j = w&3, h-half = w>>2) ----------------
    {
        const int jr = wv & 3;
        const int h2 = (wv >> 2) * 128 + 2 * lane;
        float sx = 0.f, sy = 0.f;
        #pragma unroll
        for (int ww = 0; ww < 8; ww++) {
            float2 tv = *(const float2*)&sR[ww][jr][h2];
            sx += tv.x; sy += tv.y;
        }
        float2 o; o.x = sx; o.y = sy;
        *(float2*)(out_c + (size_t)(jj0 + jr) * HH + h2) = o;
    }
}

extern "C" void kernel_launch(void* const* d_in, const int* in_sizes, int n_in,
                              void* d_out, int out_size, void* d_ws, size_t ws_size,
                              hipStream_t stream) {
    const float* enc = (const float*)d_in[0];
    const float* dec = (const float*)d_in[1];
    const float* Wa  = (const float*)d_in[2];
    const float* Ua  = (const float*)d_in[3];
    const float* Va  = (const float*)d_in[4];

    unsigned short* W4h = (unsigned short*)d_ws;          // exp2-domain fp16 (2MB)
    float* Uhe = (float*)(W4h + (size_t)BB * 64 * TE * 4); // exp2-domain fp32 (2MB)

    float* out_c = (float*)d_out;                          // [B,TD,H]
    float* out_e = out_c + (size_t)BB * TD * HH;           // [B,TD,TE]

    k_pre<<<384, 256, 0, stream>>>(enc, dec, Wa, Ua, W4h, Uhe);
    k_attn<<<BB * TD / 4, 512, 0, stream>>>(enc, W4h, Uhe, Va, out_c, out_e);
}